// Round 4
// baseline (85.405 us; speedup 1.0000x reference)
//
#include <hip/hip_runtime.h>
#include <hip/hip_cooperative_groups.h>
#include <math.h>

namespace cg = cooperative_groups;

#define NQ 10
#define BATCHN 8192
#define NBLK (BATCHN / 64)   // 128 one-wave blocks, one batch row per thread

// ---------------------------------------------------------------------------
// Analytic collapse of the circuit (verified against hand-computed sub-cases):
//
// State after encoding + ZZ layer: |psi> = (1/32) sum_j e^{i phi_j} |j>,
//   phi(s) = -pi*sum_q x_q s_q + pi*sum_{c<t} x_c x_t s_c s_t   (s_q = +/-1).
// Observable: <psi| E R'E' Rf' (-Z0) Rf E R E |psi>. Heisenberg conjugation
// through Rf, E, R, E yields 7 Pauli strings supported on qubits {0,1,2}.
// <Z0> = 0 (uniform magnitudes); for the rest Delta(phi) is linear in the
// unflipped spins, so the 1024-term sums factorize into cosine products:
//
// result = -g0 * sum_{m in {x0+x1, x0-x1}} S(m+w13) * C(m*x2)     * K(m)
//          +g1 * sum_{n in {x0+x2, x0-x2}} C(n+w13) * C(n*x1-w14) * K(n)
// with S/C = sin/cos(2pi * .), K(m) = prod_{t=3..9} C(m*x_t),
//      g0 = 0.5*cos(2pi(w0+w1+w2))*sin(2pi*w3), g1 = 0.5*sin(2pi(w0+w1+w2)).
// (w[4..12] and w[15..22] provably do not affect the output.)
//
// Single cooperative launch: the global any(in>1) flag is a grid-wide
// reduction-broadcast; grid.sync() replaces the second kernel launch.
//  - per-block flag slots are written UNCONDITIONALLY, so the poisoned
//    workspace needs no initialization (no counter-init hazard);
//  - flag loads after the sync are agent-scope atomics, so no stale
//    per-XCD-L2 line can be observed (grid.sync's fences cover the rest);
//  - 128 one-wave blocks are trivially co-resident (cooperative requirement).
// ws layout: [0..127] int per-block any(in>1) flags.
// ---------------------------------------------------------------------------

__global__ __launch_bounds__(64) void fused_kernel(const float* __restrict__ in,
                                                   const float* __restrict__ w,
                                                   int* __restrict__ flags,
                                                   float* __restrict__ out) {
    const int b = blockIdx.x * 64 + threadIdx.x;

    // own row: 5 independent float2 loads (8B-aligned, cache-line dense)
    const float2* __restrict__ r2 = (const float2*)in + (size_t)b * 5;
    const float2 p0 = r2[0], p1 = r2[1], p2 = r2[2], p3 = r2[3], p4 = r2[4];
    float x[NQ] = {p0.x, p0.y, p1.x, p1.y, p2.x, p2.y, p3.x, p3.y, p4.x, p4.y};

    float mx = x[0];
#pragma unroll
    for (int q = 1; q < NQ; ++q) mx = fmaxf(mx, x[q]);
    const int any = __any(mx > 1.0f) ? 1 : 0;
    if (threadIdx.x == 0)
        __hip_atomic_store(&flags[blockIdx.x], any, __ATOMIC_RELAXED,
                           __HIP_MEMORY_SCOPE_AGENT);

    // gate constants: uniform scalar loads + 3 HW trig (revolution units);
    // computed here to overlap other blocks' arrival at the barrier
    const float sw = w[0] + w[1] + w[2];
    const float g0 = 0.5f * __builtin_amdgcn_cosf(sw) * __builtin_amdgcn_sinf(w[3]);
    const float g1 = 0.5f * __builtin_amdgcn_sinf(sw);
    const float l0 = w[13], l1 = w[14];

    cg::this_grid().sync();

    const int f =
        __hip_atomic_load(&flags[threadIdx.x], __ATOMIC_RELAXED,
                          __HIP_MEMORY_SCOPE_AGENT) |
        __hip_atomic_load(&flags[threadIdx.x + 64], __ATOMIC_RELAXED,
                          __HIP_MEMORY_SCOPE_AGENT);
    const bool anyflag = __any(f != 0);

    if (anyflag) {
#pragma unroll
        for (int q = 0; q < NQ; ++q) x[q] = atanf(x[q]);
    }

    const float mp  = x[0] + x[1], mm = x[0] - x[1];   // F={0,1} combos
    const float np_ = x[0] + x[2], nm = x[0] - x[2];   // F={0,2} combos

    float Kmp = 1.0f, Kmm = 1.0f, Knp = 1.0f, Knm = 1.0f;
#pragma unroll
    for (int t = 3; t < NQ; ++t) {
        Kmp *= __builtin_amdgcn_cosf(mp * x[t]);
        Kmm *= __builtin_amdgcn_cosf(mm * x[t]);
        Knp *= __builtin_amdgcn_cosf(np_ * x[t]);
        Knm *= __builtin_amdgcn_cosf(nm * x[t]);
    }

    const float t1 = __builtin_amdgcn_sinf(mp + l0) * __builtin_amdgcn_cosf(mp * x[2]) * Kmp
                   + __builtin_amdgcn_sinf(mm + l0) * __builtin_amdgcn_cosf(mm * x[2]) * Kmm;
    const float t2 = __builtin_amdgcn_cosf(np_ + l0) * __builtin_amdgcn_cosf(np_ * x[1] - l1) * Knp
                   + __builtin_amdgcn_cosf(nm + l0) * __builtin_amdgcn_cosf(nm * x[1] - l1) * Knm;

    out[b] = fmaf(-g0, t1, g1 * t2);
}

extern "C" void kernel_launch(void* const* d_in, const int* in_sizes, int n_in,
                              void* d_out, int out_size, void* d_ws, size_t ws_size,
                              hipStream_t stream) {
    const float* inputs = (const float*)d_in[0];   // (8192, 10) float32
    const float* weight = (const float*)d_in[1];   // (23,) float32
    // d_in[2] = entangle_matrix — folded analytically (Clifford conjugation), unused.
    float* out   = (float*)d_out;                  // (8192,) float32
    int*   flags = (int*)d_ws;                     // 128 ints (rewritten every launch)

    void* args[] = {(void*)&inputs, (void*)&weight, (void*)&flags, (void*)&out};
    hipLaunchCooperativeKernel((const void*)fused_kernel, dim3(NBLK), dim3(64),
                               args, 0, stream);
}

// Round 5
// 63.368 us; speedup vs baseline: 1.3478x; 1.3478x over previous
//
#include <hip/hip_runtime.h>
#include <math.h>

#define NQ 10
#define BATCHN 8192
#define NBLK 32                     // 32 blocks x 256 threads = 8192 rows
#define NSLOT 128                   // 4 waves/block x 32 blocks

#define MAGIC_A 0x9E3779B9u
#define MAGIC_B 0x85EBCA6Bu
#define MAGXOR  (MAGIC_A ^ MAGIC_B)

// ---------------------------------------------------------------------------
// Analytic collapse of the circuit (verified against hand-computed sub-cases):
//
// State after encoding + ZZ layer: |psi> = (1/32) sum_j e^{i phi_j} |j>,
//   phi(s) = -pi*sum_q x_q s_q + pi*sum_{c<t} x_c x_t s_c s_t   (s_q = +/-1).
// Observable: <psi| E R'E' Rf' (-Z0) Rf E R E |psi>. Heisenberg conjugation
// through Rf, E, R, E yields 7 Pauli strings supported on qubits {0,1,2}.
// <Z0> = 0 (uniform magnitudes); for the rest Delta(phi) is linear in the
// unflipped spins, so the 1024-term sums factorize into cosine products:
//
// result = -g0 * sum_{m in {x0+x1, x0-x1}} S(m+w13) * C(m*x2)     * K(m)
//          +g1 * sum_{n in {x0+x2, x0-x2}} C(n+w13) * C(n*x1-w14) * K(n)
// with S/C = sin/cos(2pi * .), K(m) = prod_{t=3..9} C(m*x_t),
//      g0 = 0.5*cos(2pi(w0+w1+w2))*sin(2pi*w3), g1 = 0.5*sin(2pi(w0+w1+w2)).
// (w[4..12] and w[15..22] provably do not affect the output.)
//
// SINGLE plain launch (cooperative launch is not graph-capturable -> round-4
// regression). The global any(in>1) reduction-broadcast uses a spin on
// self-validating 64-bit flag words:
//   slot value = ((MAGIC_B^any)<<32) | (MAGIC_A^any);  valid iff hi^lo==A^B.
//   Workspace poison is a repeating 32-bit fill pattern -> hi==lo -> hi^lo==0
//   != A^B: poison can NEVER validate, for any fill value; the any bit
//   XOR-cancels out of the validity check. No init, no fence needed (the
//   flag word is the only communicated datum and is a single 64b atomic).
// 32 blocks on 256 CUs are always co-resident -> the spin cannot deadlock.
// ws layout: [0..127] u64 per-wave flag words (rewritten every launch).
// ---------------------------------------------------------------------------

__global__ __launch_bounds__(256) void fused_kernel(const float* __restrict__ in,
                                                    const float* __restrict__ w,
                                                    unsigned long long* __restrict__ fl,
                                                    float* __restrict__ out) {
    const int b    = blockIdx.x * 256 + threadIdx.x;
    const int lane = threadIdx.x & 63;

    // own row: 5 independent float2 loads (8B-aligned, cache-line dense)
    const float2* __restrict__ r2 = (const float2*)in + (size_t)b * 5;
    const float2 p0 = r2[0], p1 = r2[1], p2 = r2[2], p3 = r2[3], p4 = r2[4];
    float x[NQ] = {p0.x, p0.y, p1.x, p1.y, p2.x, p2.y, p3.x, p3.y, p4.x, p4.y};

    // per-wave any(x > 1) -> unconditional self-validating flag store
    float mx = x[0];
#pragma unroll
    for (int q = 1; q < NQ; ++q) mx = fmaxf(mx, x[q]);
    const unsigned any = __any(mx > 1.0f) ? 1u : 0u;
    if (lane == 0) {
        const int slot = blockIdx.x * 4 + (threadIdx.x >> 6);
        const unsigned long long v =
            ((unsigned long long)(MAGIC_B ^ any) << 32) | (MAGIC_A ^ any);
        __hip_atomic_store(&fl[slot], v, __ATOMIC_RELAXED,
                           __HIP_MEMORY_SCOPE_AGENT);
    }

    // gate constants: uniform scalar loads + 3 HW trig (revolution units);
    // computed before the spin to hide other blocks' dispatch skew
    const float sw = w[0] + w[1] + w[2];
    const float g0 = 0.5f * __builtin_amdgcn_cosf(sw) * __builtin_amdgcn_sinf(w[3]);
    const float g1 = 0.5f * __builtin_amdgcn_sinf(sw);
    const float l0 = w[13], l1 = w[14];

    // spin until all 128 slots validate; OR the any-bits (2 slots per lane)
    unsigned f = 0;
#pragma unroll
    for (int s = 0; s < 2; ++s) {
        const int slot = lane + 64 * s;
        unsigned long long v;
        do {
            v = __hip_atomic_load(&fl[slot], __ATOMIC_RELAXED,
                                  __HIP_MEMORY_SCOPE_AGENT);
        } while ((((unsigned)(v >> 32)) ^ ((unsigned)v)) != MAGXOR);
        f |= ((unsigned)v) ^ MAGIC_A;
    }
    const bool anyflag = __any(f != 0);

    if (anyflag) {
#pragma unroll
        for (int q = 0; q < NQ; ++q) x[q] = atanf(x[q]);
    }

    const float mp  = x[0] + x[1], mm = x[0] - x[1];   // F={0,1} combos
    const float np_ = x[0] + x[2], nm = x[0] - x[2];   // F={0,2} combos

    float Kmp = 1.0f, Kmm = 1.0f, Knp = 1.0f, Knm = 1.0f;
#pragma unroll
    for (int t = 3; t < NQ; ++t) {
        Kmp *= __builtin_amdgcn_cosf(mp * x[t]);
        Kmm *= __builtin_amdgcn_cosf(mm * x[t]);
        Knp *= __builtin_amdgcn_cosf(np_ * x[t]);
        Knm *= __builtin_amdgcn_cosf(nm * x[t]);
    }

    const float t1 = __builtin_amdgcn_sinf(mp + l0) * __builtin_amdgcn_cosf(mp * x[2]) * Kmp
                   + __builtin_amdgcn_sinf(mm + l0) * __builtin_amdgcn_cosf(mm * x[2]) * Kmm;
    const float t2 = __builtin_amdgcn_cosf(np_ + l0) * __builtin_amdgcn_cosf(np_ * x[1] - l1) * Knp
                   + __builtin_amdgcn_cosf(nm + l0) * __builtin_amdgcn_cosf(nm * x[1] - l1) * Knm;

    out[b] = fmaf(-g0, t1, g1 * t2);
}

extern "C" void kernel_launch(void* const* d_in, const int* in_sizes, int n_in,
                              void* d_out, int out_size, void* d_ws, size_t ws_size,
                              hipStream_t stream) {
    const float* inputs = (const float*)d_in[0];   // (8192, 10) float32
    const float* weight = (const float*)d_in[1];   // (23,) float32
    // d_in[2] = entangle_matrix — folded analytically (Clifford conjugation), unused.
    float* out = (float*)d_out;                    // (8192,) float32
    unsigned long long* fl = (unsigned long long*)d_ws;  // 128 u64 flag words

    fused_kernel<<<NBLK, 256, 0, stream>>>(inputs, weight, fl, out);
}

// Round 6
// 61.469 us; speedup vs baseline: 1.3894x; 1.0309x over previous
//
#include <hip/hip_runtime.h>
#include <math.h>

#define NQ 10
#define BATCHN 8192
#define NF4 ((BATCHN * NQ) / 4)     // 20480 float4 in the input
#define FLAGB (NF4 / 64)            // 320 one-wave flag blocks

// ---------------------------------------------------------------------------
// Analytic collapse of the circuit (verified against hand-computed sub-cases):
//
// State after encoding + ZZ layer: |psi> = (1/32) sum_j e^{i phi_j} |j>,
//   phi(s) = -pi*sum_q x_q s_q + pi*sum_{c<t} x_c x_t s_c s_t   (s_q = +/-1).
// Observable: <psi| E R'E' Rf' (-Z0) Rf E R E |psi>. Heisenberg conjugation
// through Rf, E, R, E yields 7 Pauli strings supported on qubits {0,1,2}.
// <Z0> = 0 (uniform magnitudes); for the rest Delta(phi) is linear in the
// unflipped spins, so the 1024-term sums factorize into cosine products:
//
// result = -g0 * sum_{m in {x0+x1, x0-x1}} S(m+w13) * C(m*x2)     * K(m)
//          +g1 * sum_{n in {x0+x2, x0-x2}} C(n+w13) * C(n*x1-w14) * K(n)
// with S/C = sin/cos(2pi * .), K(m) = prod_{t=3..9} C(m*x_t),
//      g0 = 0.5*cos(2pi(w0+w1+w2))*sin(2pi*w3), g1 = 0.5*sin(2pi(w0+w1+w2)).
// (w[4..12] and w[15..22] provably do not affect the output.)
//
// Two launches: the global any(in>1) flag is a grid-wide reduction that must
// complete before ANY output is written. Measured alternatives: cooperative
// launch = +25 us (not graph-capturable); single-launch spin-flag = +2.7 us;
// per-block redundant input scan = +19 us. This two-launch structure is the
// best-measured (60.7 us). Both kernels are at their latency floor:
//   flag_kernel:   1 float4 load + wave-any + 1 store per thread. No LDS/loop.
//   expect_kernel: 5 independent float2 loads (own row) + 5 flag loads + trig.
//                  No LDS, no __syncthreads.
// ws layout: [0..319] int per-wave-block any(in>1) flags.
// ---------------------------------------------------------------------------

__global__ __launch_bounds__(64) void flag_kernel(const float* __restrict__ in,
                                                  int* __restrict__ flags) {
    const float4 v = ((const float4*)in)[blockIdx.x * 64 + threadIdx.x];
    const float mx = fmaxf(fmaxf(v.x, v.y), fmaxf(v.z, v.w));
    const int any = __any(mx > 1.0f) ? 1 : 0;
    if (threadIdx.x == 0) flags[blockIdx.x] = any;
}

__global__ __launch_bounds__(256) void expect_kernel(const float* __restrict__ in,
                                                     const int* __restrict__ flags,
                                                     const float* __restrict__ w,
                                                     float* __restrict__ out) {
    const int b    = blockIdx.x * 256 + threadIdx.x;
    const int lane = threadIdx.x & 63;

    // issue own-row loads first (5 independent float2, 8B-aligned, dense lines)
    const float2* __restrict__ r2 = (const float2*)in + (size_t)b * 5;
    const float2 p0 = r2[0], p1 = r2[1], p2 = r2[2], p3 = r2[3], p4 = r2[4];

    // global any(in>1): OR-reduce the 320 per-wave flags across the wave
    int f = flags[lane] | flags[lane + 64] | flags[lane + 128]
          | flags[lane + 192] | flags[lane + 256];
    const bool anyflag = __any(f != 0);

    // gate constants: uniform scalar loads + 3 HW trig (revolution units)
    const float sw = w[0] + w[1] + w[2];
    const float g0 = 0.5f * __builtin_amdgcn_cosf(sw) * __builtin_amdgcn_sinf(w[3]);
    const float g1 = 0.5f * __builtin_amdgcn_sinf(sw);
    const float l0 = w[13], l1 = w[14];

    float x[NQ] = {p0.x, p0.y, p1.x, p1.y, p2.x, p2.y, p3.x, p3.y, p4.x, p4.y};
    if (anyflag) {
#pragma unroll
        for (int q = 0; q < NQ; ++q) x[q] = atanf(x[q]);
    }

    const float mp  = x[0] + x[1], mm = x[0] - x[1];   // F={0,1} combos
    const float np_ = x[0] + x[2], nm = x[0] - x[2];   // F={0,2} combos

    float Kmp = 1.0f, Kmm = 1.0f, Knp = 1.0f, Knm = 1.0f;
#pragma unroll
    for (int t = 3; t < NQ; ++t) {
        Kmp *= __builtin_amdgcn_cosf(mp * x[t]);
        Kmm *= __builtin_amdgcn_cosf(mm * x[t]);
        Knp *= __builtin_amdgcn_cosf(np_ * x[t]);
        Knm *= __builtin_amdgcn_cosf(nm * x[t]);
    }

    const float t1 = __builtin_amdgcn_sinf(mp + l0) * __builtin_amdgcn_cosf(mp * x[2]) * Kmp
                   + __builtin_amdgcn_sinf(mm + l0) * __builtin_amdgcn_cosf(mm * x[2]) * Kmm;
    const float t2 = __builtin_amdgcn_cosf(np_ + l0) * __builtin_amdgcn_cosf(np_ * x[1] - l1) * Knp
                   + __builtin_amdgcn_cosf(nm + l0) * __builtin_amdgcn_cosf(nm * x[1] - l1) * Knm;

    out[b] = fmaf(-g0, t1, g1 * t2);
}

extern "C" void kernel_launch(void* const* d_in, const int* in_sizes, int n_in,
                              void* d_out, int out_size, void* d_ws, size_t ws_size,
                              hipStream_t stream) {
    const float* inputs = (const float*)d_in[0];   // (8192, 10) float32
    const float* weight = (const float*)d_in[1];   // (23,) float32
    // d_in[2] = entangle_matrix — folded analytically (Clifford conjugation), unused.
    float* out   = (float*)d_out;                  // (8192,) float32
    int*   flags = (int*)d_ws;                     // 320 ints (rewritten every launch)

    flag_kernel<<<FLAGB, 64, 0, stream>>>(inputs, flags);
    expect_kernel<<<BATCHN / 256, 256, 0, stream>>>(inputs, flags, weight, out);
}